// Round 13
// baseline (541.618 us; speedup 1.0000x reference)
//
#include <hip/hip_runtime.h>

#define N_NODESC 100000
#define N_EDGESC 1600000
#define IN_DIMC 128
#define HIDC 64
#define N_GRAPHSC 512
#define PAD_DEG 64

// ---------------- setup kernels ----------------

// zero 4 cnt replicas + compute per-graph bounds (independent work, one launch)
__global__ void zero_bounds_kernel(int* __restrict__ cntR, const int* __restrict__ batch,
                                   int* __restrict__ gstart) {
  int i = blockIdx.x * blockDim.x + threadIdx.x;
  if (i >= N_NODESC) return;
  cntR[i] = 0;
  cntR[N_NODESC + i] = 0;
  cntR[2 * N_NODESC + i] = 0;
  cntR[3 * N_NODESC + i] = 0;
  int b = batch[i];
  int prev = (i == 0) ? -1 : batch[i - 1];
  for (int g = prev + 1; g <= b; ++g) gstart[g] = i;
  if (i == N_NODESC - 1)
    for (int g = b + 1; g <= N_GRAPHSC; ++g) gstart[g] = N_NODESC;
}

// per-node: exclusive prefix over replicas -> offR, total cnt, dinv
__global__ void off_dinv_kernel(const int* __restrict__ cntR, int* __restrict__ offR,
                                int* __restrict__ cnt, float* __restrict__ dinv) {
  int i = blockIdx.x * blockDim.x + threadIdx.x;
  if (i >= N_NODESC) return;
  int c0 = cntR[i];
  int c1 = cntR[N_NODESC + i];
  int c2 = cntR[2 * N_NODESC + i];
  int c3 = cntR[3 * N_NODESC + i];
  offR[i] = c0;
  offR[N_NODESC + i] = c0 + c1;
  offR[2 * N_NODESC + i] = c0 + c1 + c2;
  int tot = c0 + c1 + c2 + c3;
  cnt[i] = tot;
  dinv[i] = rsqrtf((float)tot + 1.0f);
}

// atomic-free padded placement: csr_pad[d*64 + offR[r][d] + slot_r[e]] = src
__global__ void fill_pad_kernel(const int* __restrict__ srcv, const int* __restrict__ dstv,
                                const int* __restrict__ slot, const int* __restrict__ offR,
                                int* __restrict__ csr_pad) {
  int e4 = (blockIdx.x * blockDim.x + threadIdx.x) * 4;
  if (e4 >= N_EDGESC) return;
  int4 s = *(const int4*)(srcv + e4);
  int4 d = *(const int4*)(dstv + e4);
  int4 sl = *(const int4*)(slot + e4);
  int p0 = sl.x;
  int p1 = offR[d.y] + sl.y;
  int p2 = offR[N_NODESC + d.z] + sl.z;
  int p3 = offR[2 * N_NODESC + d.w] + sl.w;
  if (p0 < PAD_DEG) __builtin_nontemporal_store(s.x, &csr_pad[d.x * PAD_DEG + p0]);
  if (p1 < PAD_DEG) __builtin_nontemporal_store(s.y, &csr_pad[d.y * PAD_DEG + p1]);
  if (p2 < PAD_DEG) __builtin_nontemporal_store(s.z, &csr_pad[d.z * PAD_DEG + p2]);
  if (p3 < PAD_DEG) __builtin_nontemporal_store(s.w, &csr_pad[d.w * PAD_DEG + p3]);
}

// ---------------- GCN layer kernels ----------------

// Tiled fp32 GEMM body: T[tile] = (X[tile] @ W) [* dinv], tile = 128x64.
#define GT_M 128
#define XS_LD 132
#define GT_BLOCKS ((N_NODESC + GT_M - 1) / GT_M)  // 782

template <int KT, bool APPLY_DINV>
__device__ __forceinline__ void gemm_tile_body(const float* __restrict__ X,
                                               const float* __restrict__ W,
                                               const float* __restrict__ dinv,
                                               float* __restrict__ T, int blk,
                                               float* __restrict__ xs, float* __restrict__ ws) {
  int t = threadIdx.x;
  int base = blk * GT_M;
  int r0 = (t >> 4) * 8;
  int c0 = (t & 15) * 4;
  float acc[8][4];
#pragma unroll
  for (int i = 0; i < 8; ++i)
#pragma unroll
    for (int j = 0; j < 4; ++j) acc[i][j] = 0.f;

  int kq = (t & 15) * 4;
  int rr = t >> 4;

  for (int kb = 0; kb < KT; kb += 64) {
    if (kb) __syncthreads();
#pragma unroll
    for (int it = 0; it < 8; ++it) {
      int r = rr + it * 16;
      int grow = base + r;
      if (grow >= N_NODESC) grow = N_NODESC - 1;
      float4 q = *(const float4*)(X + (size_t)grow * KT + kb + kq);
      xs[(kq + 0) * XS_LD + r] = q.x;
      xs[(kq + 1) * XS_LD + r] = q.y;
      xs[(kq + 2) * XS_LD + r] = q.z;
      xs[(kq + 3) * XS_LD + r] = q.w;
    }
#pragma unroll
    for (int it = 0; it < 4; ++it) {
      int idx = (it * 256 + t) * 4;
      *(float4*)(ws + idx) = *(const float4*)(W + (size_t)kb * HIDC + idx);
    }
    __syncthreads();
#pragma unroll 8
    for (int k = 0; k < 64; ++k) {
      float4 xa = *(const float4*)(xs + k * XS_LD + r0);
      float4 xb = *(const float4*)(xs + k * XS_LD + r0 + 4);
      float4 wf = *(const float4*)(ws + k * 64 + c0);
      float xf[8] = {xa.x, xa.y, xa.z, xa.w, xb.x, xb.y, xb.z, xb.w};
      float wv[4] = {wf.x, wf.y, wf.z, wf.w};
#pragma unroll
      for (int i = 0; i < 8; ++i)
#pragma unroll
        for (int j = 0; j < 4; ++j) acc[i][j] = fmaf(xf[i], wv[j], acc[i][j]);
    }
  }
#pragma unroll
  for (int i = 0; i < 8; ++i) {
    int row = base + r0 + i;
    if (row < N_NODESC) {
      float dv = APPLY_DINV ? dinv[row] : 1.0f;
      float4 o;
      o.x = acc[i][0] * dv;
      o.y = acc[i][1] * dv;
      o.z = acc[i][2] * dv;
      o.w = acc[i][3] * dv;
      *(float4*)(T + (size_t)row * HIDC + c0) = o;
    }
  }
}

template <int KT, bool APPLY_DINV>
__global__ void __launch_bounds__(256, 3)
gemm_tile_kernel(const float* __restrict__ X, const float* __restrict__ W,
                 const float* __restrict__ dinv, float* __restrict__ T) {
  __shared__ float xs[64 * XS_LD];
  __shared__ float ws[64 * 64];
  gemm_tile_body<KT, APPLY_DINV>(X, W, dinv, T, blockIdx.x, xs, ws);
}

// FUSED: blocks [0,782) run gemm1 = x @ W1 (dinv deferred to gather1, so it's
// independent of the CSR build); blocks [782,...) run the deg atomics. The
// compute-bound gemm hides inside the fabric-bound deg time on the same CUs.
template <int KT>
__global__ void __launch_bounds__(256, 3)
gemm1_deg_kernel(const float* __restrict__ X, const float* __restrict__ W,
                 float* __restrict__ T, const int* __restrict__ dstv,
                 int* __restrict__ cntR, int* __restrict__ slot) {
  __shared__ float xs[64 * XS_LD];
  __shared__ float ws[64 * 64];
  if (blockIdx.x < GT_BLOCKS) {
    gemm_tile_body<KT, false>(X, W, nullptr, T, blockIdx.x, xs, ws);
  } else {
    int e4 = ((blockIdx.x - GT_BLOCKS) * blockDim.x + threadIdx.x) * 4;
    if (e4 >= N_EDGESC) return;
    int4 d = *(const int4*)(dstv + e4);
    int4 s;
    s.x = atomicAdd(&cntR[d.x], 1);
    s.y = atomicAdd(&cntR[N_NODESC + d.y], 1);
    s.z = atomicAdd(&cntR[2 * N_NODESC + d.z], 1);
    s.w = atomicAdd(&cntR[3 * N_NODESC + d.w], 1);
    *(int4*)(slot + e4) = s;
  }
}

// h[i][j] = relu(dinv[i]*(self + sum) + b[j]).
// SCALE_SRC (layer 1): ts holds RAW x@W1; apply dinv per source row here.
template <bool SCALE_SRC>
__global__ void gather_kernel(const float* __restrict__ ts, const float* __restrict__ dinv,
                              const int* __restrict__ cnt, const int* __restrict__ csr_pad,
                              const float* __restrict__ bias, float* __restrict__ h) {
  int lane = threadIdx.x & 63;
  int node = (blockIdx.x * blockDim.x + threadIdx.x) >> 6;
  if (node >= N_NODESC) return;
  int deg = min(cnt[node], PAD_DEG);
  const int* __restrict__ row = csr_pad + node * PAD_DEG;  // wave-uniform reads
  float dvn = dinv[node];
  float self = ts[node * HIDC + lane];
  float sum = SCALE_SRC ? self * dvn : self;
  int e = 0;
  for (; e + 16 <= deg; e += 16) {
    int si[16];
#pragma unroll
    for (int j = 0; j < 16; ++j) si[j] = row[e + j];
    float dv[16];
    if (SCALE_SRC) {
#pragma unroll
      for (int j = 0; j < 16; ++j) dv[j] = dinv[si[j]];
    }
    float v[16];
#pragma unroll
    for (int j = 0; j < 16; ++j) v[j] = ts[si[j] * HIDC + lane];
    if (SCALE_SRC) {
      float s0 = 0.f, s1 = 0.f;
#pragma unroll
      for (int j = 0; j < 8; ++j) s0 = fmaf(v[j], dv[j], s0);
#pragma unroll
      for (int j = 8; j < 16; ++j) s1 = fmaf(v[j], dv[j], s1);
      sum += s0 + s1;
    } else {
      float s0 = ((v[0] + v[1]) + (v[2] + v[3])) + ((v[4] + v[5]) + (v[6] + v[7]));
      float s1 = ((v[8] + v[9]) + (v[10] + v[11])) + ((v[12] + v[13]) + (v[14] + v[15]));
      sum += s0 + s1;
    }
  }
  for (; e + 4 <= deg; e += 4) {
    int s0 = row[e], s1 = row[e + 1], s2 = row[e + 2], s3 = row[e + 3];
    float v0 = ts[s0 * HIDC + lane];
    float v1 = ts[s1 * HIDC + lane];
    float v2 = ts[s2 * HIDC + lane];
    float v3 = ts[s3 * HIDC + lane];
    if (SCALE_SRC) {
      float a = fmaf(v0, dinv[s0], v1 * dinv[s1]);
      float b = fmaf(v2, dinv[s2], v3 * dinv[s3]);
      sum += a + b;
    } else {
      sum += (v0 + v1) + (v2 + v3);
    }
  }
  for (; e < deg; ++e) {
    float v = ts[row[e] * HIDC + lane];
    sum += SCALE_SRC ? v * dinv[row[e]] : v;
  }
  h[node * HIDC + lane] = fmaxf(sum * dvn + bias[lane], 0.f);
}

// ---------------- fused readout: score + softmax + weighted max-pool + MLP ----------------
__global__ void __launch_bounds__(256)
readout_kernel(const float* __restrict__ h, const float* __restrict__ closeness,
               const float* __restrict__ Wc, const float* __restrict__ bc,
               const int* __restrict__ gstart, const float* __restrict__ Wa1,
               const float* __restrict__ ba1, const float* __restrict__ Wa2,
               const float* __restrict__ ba2, float* __restrict__ out) {
  __shared__ float sArr[1024];
  __shared__ float red[256];
  __shared__ float cross[4 * 64];
  int g = blockIdx.x;
  int t = threadIdx.x;
  int n0 = gstart[g], n1 = gstart[g + 1];
  int count = n1 - n0;
  int cap = min(count, 1024);
  float wc0 = Wc[0], wc1 = Wc[1], wc2 = Wc[2], wc3 = Wc[3], wc4 = Wc[4], bcv = bc[0];
  float lmax = -3.4e38f;
  for (int idx = t; idx < cap; idx += 256) {
    const float* c = closeness + (size_t)(n0 + idx) * 5;
    float s = fmaf(c[4], wc4, fmaf(c[3], wc3, fmaf(c[2], wc2, fmaf(c[1], wc1, fmaf(c[0], wc0, bcv)))));
    sArr[idx] = s;
    lmax = fmaxf(lmax, s);
  }
  red[t] = lmax;
  __syncthreads();
  for (int s = 128; s > 0; s >>= 1) {
    if (t < s) red[t] = fmaxf(red[t], red[t + s]);
    __syncthreads();
  }
  float m = red[0];
  __syncthreads();
  float lsum = 0.f;
  for (int idx = t; idx < cap; idx += 256) {
    float e = expf(sArr[idx] - m);
    sArr[idx] = e;
    lsum += e;
  }
  red[t] = lsum;
  __syncthreads();
  for (int s = 128; s > 0; s >>= 1) {
    if (t < s) red[t] += red[t + s];
    __syncthreads();
  }
  float scale = (count > 0) ? ((float)count / red[0]) : 0.f;
  __syncthreads();
  int wv = t >> 6, lane = t & 63;
  float pmax = 0.f;  // values nonneg (relu * positive weight)
  for (int idx = wv; idx < cap; idx += 4) {
    float w = sArr[idx] * scale;
    pmax = fmaxf(pmax, w * h[(size_t)(n0 + idx) * HIDC + lane]);
  }
  cross[wv * 64 + lane] = pmax;
  __syncthreads();
  if (wv == 0) {
    float p = fmaxf(fmaxf(cross[lane], cross[64 + lane]),
                    fmaxf(cross[128 + lane], cross[192 + lane]));
    float o = 0.f;
#pragma unroll
    for (int tt = 0; tt < 16; ++tt) {
      float prod = p * Wa1[lane * 16 + tt];
#pragma unroll
      for (int off = 32; off > 0; off >>= 1) prod += __shfl_xor(prod, off);
      float a = fmaxf(prod + ba1[tt], 0.f);
      o += a * Wa2[tt];
    }
    if (lane == 0) out[g] = o + ba2[0];
  }
}

// ---------------- launch ----------------

extern "C" void kernel_launch(void* const* d_in, const int* in_sizes, int n_in,
                              void* d_out, int out_size, void* d_ws, size_t ws_size,
                              hipStream_t stream) {
  const float* x = (const float*)d_in[0];
  const int* ei = (const int*)d_in[1];
  const float* closeness = (const float*)d_in[2];
  const int* batch = (const int*)d_in[3];
  const float* W1 = (const float*)d_in[5];
  const float* b1 = (const float*)d_in[6];
  const float* W2 = (const float*)d_in[7];
  const float* b2 = (const float*)d_in[8];
  const float* W3 = (const float*)d_in[9];
  const float* b3 = (const float*)d_in[10];
  const float* Wc = (const float*)d_in[11];
  const float* bc = (const float*)d_in[12];
  const float* Wa1 = (const float*)d_in[13];
  const float* ba1 = (const float*)d_in[14];
  const float* Wa2 = (const float*)d_in[15];
  const float* ba2 = (const float*)d_in[16];
  float* out = (float*)d_out;
  const int* srcv = ei;
  const int* dstv = ei + N_EDGESC;

  char* ws = (char*)d_ws;
  size_t off = 0;
  auto alloc = [&](size_t bytes) -> void* {
    void* p = ws + off;
    off = (off + bytes + 255) & ~(size_t)255;
    return p;
  };
  float* tbuf = (float*)alloc(sizeof(float) * N_NODESC * HIDC);   // 25.6 MB
  float* hbuf = (float*)alloc(sizeof(float) * N_NODESC * HIDC);   // 25.6 MB
  int* csr_pad = (int*)alloc(sizeof(int) * N_NODESC * PAD_DEG);   // 25.6 MB
  int* slot = (int*)alloc(sizeof(int) * N_EDGESC);                // 6.4 MB
  int* cntR = (int*)alloc(sizeof(int) * N_NODESC * 4);            // 1.6 MB
  int* offR = (int*)alloc(sizeof(int) * N_NODESC * 3);            // 1.2 MB
  int* cnt = (int*)alloc(sizeof(int) * N_NODESC);
  float* dinv = (float*)alloc(sizeof(float) * N_NODESC);
  int* gstart = (int*)alloc(sizeof(int) * (N_GRAPHSC + 1));

  const int B = 256;
  int gN = (N_NODESC + B - 1) / B;           // 391
  int gE4 = (N_EDGESC / 4 + B - 1) / B;      // 1563
  int gGather = (N_NODESC * 64) / B;         // 25000

  zero_bounds_kernel<<<gN, B, 0, stream>>>(cntR, batch, gstart);
  // fused: gemm1 (independent of CSR build, dinv deferred) + deg atomics
  gemm1_deg_kernel<IN_DIMC><<<GT_BLOCKS + gE4, B, 0, stream>>>(x, W1, tbuf, dstv, cntR, slot);
  off_dinv_kernel<<<gN, B, 0, stream>>>(cntR, offR, cnt, dinv);
  fill_pad_kernel<<<gE4, B, 0, stream>>>(srcv, dstv, slot, offR, csr_pad);

  // layer 1 gather applies dinv per source row (ts is raw x@W1)
  gather_kernel<true><<<gGather, B, 0, stream>>>(tbuf, dinv, cnt, csr_pad, b1, hbuf);
  // layer 2
  gemm_tile_kernel<HIDC, true><<<GT_BLOCKS, B, 0, stream>>>(hbuf, W2, dinv, tbuf);
  gather_kernel<false><<<gGather, B, 0, stream>>>(tbuf, dinv, cnt, csr_pad, b2, hbuf);
  // layer 3
  gemm_tile_kernel<HIDC, true><<<GT_BLOCKS, B, 0, stream>>>(hbuf, W3, dinv, tbuf);
  gather_kernel<false><<<gGather, B, 0, stream>>>(tbuf, dinv, cnt, csr_pad, b3, hbuf);

  // fused readout
  readout_kernel<<<N_GRAPHSC, B, 0, stream>>>(hbuf, closeness, Wc, bc, gstart,
                                              Wa1, ba1, Wa2, ba2, out);
}

// Round 14
// 514.918 us; speedup vs baseline: 1.0519x; 1.0519x over previous
//
#include <hip/hip_runtime.h>

#define N_NODESC 100000
#define N_EDGESC 1600000
#define IN_DIMC 128
#define HIDC 64
#define N_GRAPHSC 512
#define PAD_DEG 64

// ---------------- setup kernels ----------------

// zero 4 cnt replicas + compute per-graph bounds (independent work, one launch)
__global__ void zero_bounds_kernel(int* __restrict__ cntR, const int* __restrict__ batch,
                                   int* __restrict__ gstart) {
  int i = blockIdx.x * blockDim.x + threadIdx.x;
  if (i >= N_NODESC) return;
  cntR[i] = 0;
  cntR[N_NODESC + i] = 0;
  cntR[2 * N_NODESC + i] = 0;
  cntR[3 * N_NODESC + i] = 0;
  int b = batch[i];
  int prev = (i == 0) ? -1 : batch[i - 1];
  for (int g = prev + 1; g <= b; ++g) gstart[g] = i;
  if (i == N_NODESC - 1)
    for (int g = b + 1; g <= N_GRAPHSC; ++g) gstart[g] = N_NODESC;
}

// degree count into 4 replicas (cuts per-line RMW serialization 4x).
// DO NOT fuse with LDS-heavy kernels: R13 measured occupancy collapse (28%).
__global__ void deg_kernel(const int* __restrict__ dstv, int* __restrict__ cntR,
                           int* __restrict__ slot) {
  int e4 = (blockIdx.x * blockDim.x + threadIdx.x) * 4;
  if (e4 >= N_EDGESC) return;
  int4 d = *(const int4*)(dstv + e4);
  int4 s;
  s.x = atomicAdd(&cntR[d.x], 1);
  s.y = atomicAdd(&cntR[N_NODESC + d.y], 1);
  s.z = atomicAdd(&cntR[2 * N_NODESC + d.z], 1);
  s.w = atomicAdd(&cntR[3 * N_NODESC + d.w], 1);
  *(int4*)(slot + e4) = s;
}

// per-node: exclusive prefix over replicas -> offR, total cnt, dinv
__global__ void off_dinv_kernel(const int* __restrict__ cntR, int* __restrict__ offR,
                                int* __restrict__ cnt, float* __restrict__ dinv) {
  int i = blockIdx.x * blockDim.x + threadIdx.x;
  if (i >= N_NODESC) return;
  int c0 = cntR[i];
  int c1 = cntR[N_NODESC + i];
  int c2 = cntR[2 * N_NODESC + i];
  int c3 = cntR[3 * N_NODESC + i];
  offR[i] = c0;
  offR[N_NODESC + i] = c0 + c1;
  offR[2 * N_NODESC + i] = c0 + c1 + c2;
  int tot = c0 + c1 + c2 + c3;
  cnt[i] = tot;
  dinv[i] = rsqrtf((float)tot + 1.0f);
}

// atomic-free padded placement: csr_pad[d*64 + offR[r][d] + slot_r[e]] = src
__global__ void fill_pad_kernel(const int* __restrict__ srcv, const int* __restrict__ dstv,
                                const int* __restrict__ slot, const int* __restrict__ offR,
                                int* __restrict__ csr_pad) {
  int e4 = (blockIdx.x * blockDim.x + threadIdx.x) * 4;
  if (e4 >= N_EDGESC) return;
  int4 s = *(const int4*)(srcv + e4);
  int4 d = *(const int4*)(dstv + e4);
  int4 sl = *(const int4*)(slot + e4);
  int p0 = sl.x;
  int p1 = offR[d.y] + sl.y;
  int p2 = offR[N_NODESC + d.z] + sl.z;
  int p3 = offR[2 * N_NODESC + d.w] + sl.w;
  if (p0 < PAD_DEG) __builtin_nontemporal_store(s.x, &csr_pad[d.x * PAD_DEG + p0]);
  if (p1 < PAD_DEG) __builtin_nontemporal_store(s.y, &csr_pad[d.y * PAD_DEG + p1]);
  if (p2 < PAD_DEG) __builtin_nontemporal_store(s.z, &csr_pad[d.z * PAD_DEG + p2]);
  if (p3 < PAD_DEG) __builtin_nontemporal_store(s.w, &csr_pad[d.w * PAD_DEG + p3]);
}

// ---------------- GCN layer kernels ----------------

// Tiled fp32 GEMM: T[tile] = (X[tile] @ W) * dinv, tile = 128x64.
#define GT_M 128
#define XS_LD 132
#define GT_BLOCKS ((N_NODESC + GT_M - 1) / GT_M)  // 782

template <int KT>
__global__ void __launch_bounds__(256, 3)
gemm_tile_kernel(const float* __restrict__ X, const float* __restrict__ W,
                 const float* __restrict__ dinv, float* __restrict__ T) {
  __shared__ float xs[64 * XS_LD];
  __shared__ float ws[64 * 64];
  int t = threadIdx.x;
  int base = blockIdx.x * GT_M;
  int r0 = (t >> 4) * 8;
  int c0 = (t & 15) * 4;
  float acc[8][4];
#pragma unroll
  for (int i = 0; i < 8; ++i)
#pragma unroll
    for (int j = 0; j < 4; ++j) acc[i][j] = 0.f;

  int kq = (t & 15) * 4;
  int rr = t >> 4;

  for (int kb = 0; kb < KT; kb += 64) {
    if (kb) __syncthreads();
#pragma unroll
    for (int it = 0; it < 8; ++it) {
      int r = rr + it * 16;
      int grow = base + r;
      if (grow >= N_NODESC) grow = N_NODESC - 1;
      float4 q = *(const float4*)(X + (size_t)grow * KT + kb + kq);
      xs[(kq + 0) * XS_LD + r] = q.x;
      xs[(kq + 1) * XS_LD + r] = q.y;
      xs[(kq + 2) * XS_LD + r] = q.z;
      xs[(kq + 3) * XS_LD + r] = q.w;
    }
#pragma unroll
    for (int it = 0; it < 4; ++it) {
      int idx = (it * 256 + t) * 4;
      *(float4*)(ws + idx) = *(const float4*)(W + (size_t)kb * HIDC + idx);
    }
    __syncthreads();
#pragma unroll 8
    for (int k = 0; k < 64; ++k) {
      float4 xa = *(const float4*)(xs + k * XS_LD + r0);
      float4 xb = *(const float4*)(xs + k * XS_LD + r0 + 4);
      float4 wf = *(const float4*)(ws + k * 64 + c0);
      float xf[8] = {xa.x, xa.y, xa.z, xa.w, xb.x, xb.y, xb.z, xb.w};
      float wv[4] = {wf.x, wf.y, wf.z, wf.w};
#pragma unroll
      for (int i = 0; i < 8; ++i)
#pragma unroll
        for (int j = 0; j < 4; ++j) acc[i][j] = fmaf(xf[i], wv[j], acc[i][j]);
    }
  }
#pragma unroll
  for (int i = 0; i < 8; ++i) {
    int row = base + r0 + i;
    if (row < N_NODESC) {
      float dv = dinv[row];
      float4 o;
      o.x = acc[i][0] * dv;
      o.y = acc[i][1] * dv;
      o.z = acc[i][2] * dv;
      o.w = acc[i][3] * dv;
      *(float4*)(T + (size_t)row * HIDC + c0) = o;
    }
  }
}

// h[i][:] = relu(dinv[i]*(ts[i][:] + sum_{s in pad-row i} ts[s][:]) + b)
// Wave layout: lane l = (quarter q=l>>4, col-quad c=l&15). One float4 LOAD
// INSTRUCTION fetches 4 source rows (16B/lane, 1KB/instr) -- 4x the bytes in
// flight of the 4B/lane version (measured 3.4 TB/s, suspected concurrency-bound).
// Quarter partials folded with shfl_xor(16/32) once per node.
__global__ void gather_kernel(const float* __restrict__ ts, const float* __restrict__ dinv,
                              const int* __restrict__ cnt, const int* __restrict__ csr_pad,
                              const float* __restrict__ bias, float* __restrict__ h) {
  int lane = threadIdx.x & 63;
  int node = (blockIdx.x * blockDim.x + threadIdx.x) >> 6;
  if (node >= N_NODESC) return;
  int q = lane >> 4;        // quarter: which of 4 concurrent edges
  int c = lane & 15;        // col-quad: features 4c..4c+3
  int deg = min(cnt[node], PAD_DEG);
  const int* __restrict__ row = csr_pad + node * PAD_DEG;
  const float4* __restrict__ ts4 = (const float4*)ts;
  float4 acc = make_float4(0.f, 0.f, 0.f, 0.f);
  int e = 0;
  // 16 edges per block: 4 idx loads + 4 float4 loads (16KB in flight across unroll)
  for (; e + 16 <= deg; e += 16) {
    int s0 = row[e + q];
    int s1 = row[e + 4 + q];
    int s2 = row[e + 8 + q];
    int s3 = row[e + 12 + q];
    float4 v0 = ts4[s0 * 16 + c];
    float4 v1 = ts4[s1 * 16 + c];
    float4 v2 = ts4[s2 * 16 + c];
    float4 v3 = ts4[s3 * 16 + c];
    acc.x += (v0.x + v1.x) + (v2.x + v3.x);
    acc.y += (v0.y + v1.y) + (v2.y + v3.y);
    acc.z += (v0.z + v1.z) + (v2.z + v3.z);
    acc.w += (v0.w + v1.w) + (v2.w + v3.w);
  }
  for (; e + 4 <= deg; e += 4) {
    int s0 = row[e + q];
    float4 v = ts4[s0 * 16 + c];
    acc.x += v.x;
    acc.y += v.y;
    acc.z += v.z;
    acc.w += v.w;
  }
  if (e < deg && q < deg - e) {  // tail 1..3 edges, quarters 0..r-1 active
    int s0 = row[e + q];
    float4 v = ts4[s0 * 16 + c];
    acc.x += v.x;
    acc.y += v.y;
    acc.z += v.z;
    acc.w += v.w;
  }
  // fold quarters: lanes ^16 then ^32
  acc.x += __shfl_xor(acc.x, 16);
  acc.y += __shfl_xor(acc.y, 16);
  acc.z += __shfl_xor(acc.z, 16);
  acc.w += __shfl_xor(acc.w, 16);
  acc.x += __shfl_xor(acc.x, 32);
  acc.y += __shfl_xor(acc.y, 32);
  acc.z += __shfl_xor(acc.z, 32);
  acc.w += __shfl_xor(acc.w, 32);
  if (q == 0) {
    float4 self = ts4[node * 16 + c];
    float4 bv = ((const float4*)bias)[c];
    float dv = dinv[node];
    float4 o;
    o.x = fmaxf(fmaf(acc.x + self.x, dv, bv.x), 0.f);
    o.y = fmaxf(fmaf(acc.y + self.y, dv, bv.y), 0.f);
    o.z = fmaxf(fmaf(acc.z + self.z, dv, bv.z), 0.f);
    o.w = fmaxf(fmaf(acc.w + self.w, dv, bv.w), 0.f);
    ((float4*)h)[node * 16 + c] = o;
  }
}

// ---------------- fused readout: score + softmax + weighted max-pool + MLP ----------------
__global__ void __launch_bounds__(256)
readout_kernel(const float* __restrict__ h, const float* __restrict__ closeness,
               const float* __restrict__ Wc, const float* __restrict__ bc,
               const int* __restrict__ gstart, const float* __restrict__ Wa1,
               const float* __restrict__ ba1, const float* __restrict__ Wa2,
               const float* __restrict__ ba2, float* __restrict__ out) {
  __shared__ float sArr[1024];
  __shared__ float red[256];
  __shared__ float cross[4 * 64];
  int g = blockIdx.x;
  int t = threadIdx.x;
  int n0 = gstart[g], n1 = gstart[g + 1];
  int count = n1 - n0;
  int cap = min(count, 1024);
  float wc0 = Wc[0], wc1 = Wc[1], wc2 = Wc[2], wc3 = Wc[3], wc4 = Wc[4], bcv = bc[0];
  float lmax = -3.4e38f;
  for (int idx = t; idx < cap; idx += 256) {
    const float* c = closeness + (size_t)(n0 + idx) * 5;
    float s = fmaf(c[4], wc4, fmaf(c[3], wc3, fmaf(c[2], wc2, fmaf(c[1], wc1, fmaf(c[0], wc0, bcv)))));
    sArr[idx] = s;
    lmax = fmaxf(lmax, s);
  }
  red[t] = lmax;
  __syncthreads();
  for (int s = 128; s > 0; s >>= 1) {
    if (t < s) red[t] = fmaxf(red[t], red[t + s]);
    __syncthreads();
  }
  float m = red[0];
  __syncthreads();
  float lsum = 0.f;
  for (int idx = t; idx < cap; idx += 256) {
    float e = expf(sArr[idx] - m);
    sArr[idx] = e;
    lsum += e;
  }
  red[t] = lsum;
  __syncthreads();
  for (int s = 128; s > 0; s >>= 1) {
    if (t < s) red[t] += red[t + s];
    __syncthreads();
  }
  float scale = (count > 0) ? ((float)count / red[0]) : 0.f;
  __syncthreads();
  int wv = t >> 6, lane = t & 63;
  float pmax = 0.f;  // values nonneg (relu * positive weight)
  for (int idx = wv; idx < cap; idx += 4) {
    float w = sArr[idx] * scale;
    pmax = fmaxf(pmax, w * h[(size_t)(n0 + idx) * HIDC + lane]);
  }
  cross[wv * 64 + lane] = pmax;
  __syncthreads();
  if (wv == 0) {
    float p = fmaxf(fmaxf(cross[lane], cross[64 + lane]),
                    fmaxf(cross[128 + lane], cross[192 + lane]));
    float o = 0.f;
#pragma unroll
    for (int tt = 0; tt < 16; ++tt) {
      float prod = p * Wa1[lane * 16 + tt];
#pragma unroll
      for (int off = 32; off > 0; off >>= 1) prod += __shfl_xor(prod, off);
      float a = fmaxf(prod + ba1[tt], 0.f);
      o += a * Wa2[tt];
    }
    if (lane == 0) out[g] = o + ba2[0];
  }
}

// ---------------- launch ----------------

extern "C" void kernel_launch(void* const* d_in, const int* in_sizes, int n_in,
                              void* d_out, int out_size, void* d_ws, size_t ws_size,
                              hipStream_t stream) {
  const float* x = (const float*)d_in[0];
  const int* ei = (const int*)d_in[1];
  const float* closeness = (const float*)d_in[2];
  const int* batch = (const int*)d_in[3];
  const float* W1 = (const float*)d_in[5];
  const float* b1 = (const float*)d_in[6];
  const float* W2 = (const float*)d_in[7];
  const float* b2 = (const float*)d_in[8];
  const float* W3 = (const float*)d_in[9];
  const float* b3 = (const float*)d_in[10];
  const float* Wc = (const float*)d_in[11];
  const float* bc = (const float*)d_in[12];
  const float* Wa1 = (const float*)d_in[13];
  const float* ba1 = (const float*)d_in[14];
  const float* Wa2 = (const float*)d_in[15];
  const float* ba2 = (const float*)d_in[16];
  float* out = (float*)d_out;
  const int* srcv = ei;
  const int* dstv = ei + N_EDGESC;

  char* ws = (char*)d_ws;
  size_t off = 0;
  auto alloc = [&](size_t bytes) -> void* {
    void* p = ws + off;
    off = (off + bytes + 255) & ~(size_t)255;
    return p;
  };
  float* tbuf = (float*)alloc(sizeof(float) * N_NODESC * HIDC);   // 25.6 MB
  float* hbuf = (float*)alloc(sizeof(float) * N_NODESC * HIDC);   // 25.6 MB
  int* csr_pad = (int*)alloc(sizeof(int) * N_NODESC * PAD_DEG);   // 25.6 MB
  int* slot = (int*)alloc(sizeof(int) * N_EDGESC);                // 6.4 MB
  int* cntR = (int*)alloc(sizeof(int) * N_NODESC * 4);            // 1.6 MB
  int* offR = (int*)alloc(sizeof(int) * N_NODESC * 3);            // 1.2 MB
  int* cnt = (int*)alloc(sizeof(int) * N_NODESC);
  float* dinv = (float*)alloc(sizeof(float) * N_NODESC);
  int* gstart = (int*)alloc(sizeof(int) * (N_GRAPHSC + 1));

  const int B = 256;
  int gN = (N_NODESC + B - 1) / B;           // 391
  int gE4 = (N_EDGESC / 4 + B - 1) / B;      // 1563
  int gGather = (N_NODESC * 64) / B;         // 25000

  zero_bounds_kernel<<<gN, B, 0, stream>>>(cntR, batch, gstart);
  deg_kernel<<<gE4, B, 0, stream>>>(dstv, cntR, slot);
  off_dinv_kernel<<<gN, B, 0, stream>>>(cntR, offR, cnt, dinv);
  fill_pad_kernel<<<gE4, B, 0, stream>>>(srcv, dstv, slot, offR, csr_pad);

  // layer 1 (K=128 handled inside the tile kernel)
  gemm_tile_kernel<IN_DIMC><<<GT_BLOCKS, B, 0, stream>>>(x, W1, dinv, tbuf);
  gather_kernel<<<gGather, B, 0, stream>>>(tbuf, dinv, cnt, csr_pad, b1, hbuf);
  // layer 2
  gemm_tile_kernel<HIDC><<<GT_BLOCKS, B, 0, stream>>>(hbuf, W2, dinv, tbuf);
  gather_kernel<<<gGather, B, 0, stream>>>(tbuf, dinv, cnt, csr_pad, b2, hbuf);
  // layer 3
  gemm_tile_kernel<HIDC><<<GT_BLOCKS, B, 0, stream>>>(hbuf, W3, dinv, tbuf);
  gather_kernel<<<gGather, B, 0, stream>>>(tbuf, dinv, cnt, csr_pad, b3, hbuf);

  // fused readout
  readout_kernel<<<N_GRAPHSC, B, 0, stream>>>(hbuf, closeness, Wc, bc, gstart,
                                              Wa1, ba1, Wa2, ba2, out);
}